// Round 2
// baseline (402.857 us; speedup 1.0000x reference)
//
#include <hip/hip_runtime.h>

// Problem constants
#define HDIM 256
#define WDIM 1216
#define HWC  (HDIM*WDIM)     // 311296
#define NPTS 40000
#define KNN  9
#define CCH  64
#define PIXR 256             // index range of pixel coords (0..255)

typedef float v2f __attribute__((ext_vector_type(2)));

static __device__ __forceinline__ v2f mk2(float a, float b) { v2f r; r.x = a; r.y = b; return r; }

// ---------------------------------------------------------------------------
// Kernel 1: transpose accessed feature subregion CHW -> (iy,ix,c), ix<256.
// LDS-tiled: coalesced 256B reads AND writes; +1 pad kills bank conflicts.
// Grid: 1024 blocks (iy 0..255 x 4 ix-tiles of 64), 256 threads.
// ---------------------------------------------------------------------------
__global__ __launch_bounds__(256) void transpose_feat(const float* __restrict__ feat,
                                                      float* __restrict__ feat_t) {
    __shared__ float tile[64][65];
    const int iy   = blockIdx.x >> 2;
    const int ixb  = (blockIdx.x & 3) * 64;
    const int lane = threadIdx.x & 63;
    const int w    = threadIdx.x >> 6;
#pragma unroll
    for (int r = 0; r < 16; ++r) {
        int cc = w * 16 + r;
        tile[cc][lane] = feat[cc * HWC + iy * WDIM + ixb + lane];   // 256B coalesced
    }
    __syncthreads();
#pragma unroll
    for (int r = 0; r < 16; ++r) {
        int ix = w * 16 + r;
        feat_t[(iy * PIXR + ixb + ix) * 64 + lane] = tile[lane][ix]; // 256B coalesced
    }
}

// ---------------------------------------------------------------------------
// Kernel 2: last-wins winner per output pixel (numpy fancy-assignment semantics)
// ---------------------------------------------------------------------------
__global__ void winner_k(const int* __restrict__ pix, int* __restrict__ winner) {
    int n = blockIdx.x * 256 + threadIdx.x;
    if (n < NPTS) {
        int px = pix[2 * n];
        int py = pix[2 * n + 1];
        atomicMax(&winner[py * PIXR + px], n);
    }
}

// ---------------------------------------------------------------------------
// Kernel 3: main fused kernel. Wave per point, lane = channel c.
// Grid: 2500 blocks x 256 threads; each wave handles 4 points (16/block).
// No intra-loop barriers: msg_lds[w] is private to wave w (same-wave lgkmcnt
// ordering is sufficient).
// ---------------------------------------------------------------------------
__global__ __launch_bounds__(256, 4) void main_k(
    const float* __restrict__ feat_t,   // [256*256, 64]
    const float* __restrict__ diff,     // [N, 9, 3]
    const int*   __restrict__ nnpix,    // [N, 9, 2]
    const float* __restrict__ W1,       // [3, 32]
    const float* __restrict__ b1,       // [32]
    const float* __restrict__ W2,       // [32, 64]
    const float* __restrict__ b2,       // [64]
    const float* __restrict__ conv_w,   // [64, 64] (out, in)
    const float* __restrict__ conv_b,   // [64]
    float* __restrict__ y_buf,          // [N, 64] pre-BN output
    float* __restrict__ sums)           // [128]: sum(y), sum(y^2) per channel
{
    __shared__ float msg_lds[4][64];
    __shared__ float r1[4][64];
    __shared__ float r2[4][64];

    const int c = threadIdx.x & 63;
    const int w = __builtin_amdgcn_readfirstlane(threadIdx.x >> 6);   // wave id, scalar

    // --- persistent per-lane preloads (loop-invariant across the 4 points) ---
    float w2col[32];                       // W2[:, c]
#pragma unroll
    for (int j = 0; j < 32; ++j) w2col[j] = W2[j * 64 + c];

    float4 cw[16];                         // conv_w[c, :]
    const float4* cwrow = (const float4*)(conv_w + c * 64);
#pragma unroll
    for (int q = 0; q < 16; ++q) cw[q] = cwrow[q];

    const float b2c = b2[c];
    const float cbc = conv_b[c];

    float s1 = 0.f, s2 = 0.f;

    for (int g = 0; g < 4; ++g) {
        const int n = blockIdx.x * 16 + g * 4 + w;   // scalar point index

        // --- issue gather loads early (latency hidden under MLP compute) ---
        const int* qi = nnpix + n * 18;
        float fval[KNN];
#pragma unroll
        for (int k = 0; k < KNN; ++k) {
            int ix = qi[2 * k];
            int iy = qi[2 * k + 1];
            fval[k] = feat_t[(iy * PIXR + ix) * 64 + c];
        }

        // --- load 9x3 offsets, packed in k-pairs for v_pk_fma_f32 ---
        const float* pp = diff + n * 27;
        v2f P0[4], P1[4], P2[4];
#pragma unroll
        for (int kp = 0; kp < 4; ++kp) {
            P0[kp] = mk2(pp[6 * kp + 0], pp[6 * kp + 3]);
            P1[kp] = mk2(pp[6 * kp + 1], pp[6 * kp + 4]);
            P2[kp] = mk2(pp[6 * kp + 2], pp[6 * kp + 5]);
        }
        const float p0t = pp[24], p1t = pp[25], p2t = pp[26];

        v2f acc2[4];
#pragma unroll
        for (int kp = 0; kp < 4; ++kp) acc2[kp] = mk2(b2c, b2c);
        float acc8 = b2c;

        // --- MLP: j outer (W1/b1 wave-uniform -> s_loads), k inner ---
#pragma unroll
        for (int j = 0; j < 32; ++j) {
            const float w10 = W1[j], w11 = W1[32 + j], w12 = W1[64 + j], bj = b1[j];
            const float w2v = w2col[j];
            const v2f w10p = mk2(w10, w10), w11p = mk2(w11, w11), w12p = mk2(w12, w12);
            const v2f bjp = mk2(bj, bj), w2p = mk2(w2v, w2v);
#pragma unroll
            for (int kp = 0; kp < 4; ++kp) {
                v2f hm = P0[kp] * w10p + P1[kp] * w11p + P2[kp] * w12p + bjp;
                hm = __builtin_elementwise_max(hm, mk2(0.f, 0.f));
                acc2[kp] += hm * w2p;
            }
            float hm8 = fmaf(p0t, w10, fmaf(p1t, w11, fmaf(p2t, w12, bj)));
            hm8 = fmaxf(hm8, 0.f);
            acc8 = fmaf(hm8, w2v, acc8);
        }

        // --- weighted neighbor sum: msg[c] = sum_k relu(wts) * f ---
        float wk[KNN];
        wk[0] = acc2[0].x; wk[1] = acc2[0].y; wk[2] = acc2[1].x; wk[3] = acc2[1].y;
        wk[4] = acc2[2].x; wk[5] = acc2[2].y; wk[6] = acc2[3].x; wk[7] = acc2[3].y;
        wk[8] = acc8;
        float msg = 0.f;
#pragma unroll
        for (int k = 0; k < KNN; ++k) msg = fmaf(fmaxf(wk[k], 0.f), fval[k], msg);

        // --- 1x1 conv: y[c] = conv_b[c] + sum_c' msg[c'] * conv_w[c,c'] ---
        // msg_lds[w] is wave-private: no __syncthreads needed (same-wave lgkmcnt).
        msg_lds[w][c] = msg;
        float y = cbc;
        const float4* ml = (const float4*)msg_lds[w];
#pragma unroll
        for (int q = 0; q < 16; ++q) {
            float4 m4 = ml[q];
            float4 c4 = cw[q];
            y = fmaf(m4.x, c4.x, y);
            y = fmaf(m4.y, c4.y, y);
            y = fmaf(m4.z, c4.z, y);
            y = fmaf(m4.w, c4.w, y);
        }

        s1 += y;
        s2 = fmaf(y, y, s2);
        y_buf[n * 64 + c] = y;
    }

    // --- block reduction of BN partials, one atomicAdd pair per lane of wave 0 ---
    r1[w][c] = s1;
    r2[w][c] = s2;
    __syncthreads();
    if (w == 0) {
        float a  = r1[0][c] + r1[1][c] + r1[2][c] + r1[3][c];
        float bb = r2[0][c] + r2[1][c] + r2[2][c] + r2[3][c];
        atomicAdd(&sums[c], a);
        atomicAdd(&sums[64 + c], bb);
    }
}

// ---------------------------------------------------------------------------
// Kernel 4: fold BN stats into per-channel affine: A = gamma*rstd, B = beta - mean*A
// ---------------------------------------------------------------------------
__global__ void stats_k(const float* __restrict__ sums, const float* __restrict__ gamma,
                        const float* __restrict__ beta, float* __restrict__ ab) {
    int c = threadIdx.x;
    const float inv_n = 1.f / (float)NPTS;
    float mean = sums[c] * inv_n;
    float var  = sums[64 + c] * inv_n - mean * mean;
    float rstd = rsqrtf(var + 1e-5f);
    float A = gamma[c] * rstd;
    ab[c] = A;
    ab[64 + c] = beta[c] - mean * A;
}

// ---------------------------------------------------------------------------
// Kernel 5: BN apply + relu + last-wins scatter. Wave per point: pix/winner
// loads are wave-uniform (scalar), y_buf read coalesced, skipped for losers.
// Grid: 10000 blocks x 256 threads (4 points/block).
// ---------------------------------------------------------------------------
__global__ __launch_bounds__(256) void apply_k(const float* __restrict__ y_buf,
                                               const float* __restrict__ ab,
                                               const int* __restrict__ pix,
                                               const int* __restrict__ winner,
                                               float* __restrict__ out) {
    const int c = threadIdx.x & 63;
    const int w = __builtin_amdgcn_readfirstlane(threadIdx.x >> 6);
    const int n = blockIdx.x * 4 + w;          // scalar point index
    const int px = pix[2 * n];                 // wave-uniform -> s_load
    const int py = pix[2 * n + 1];
    if (winner[py * PIXR + px] == n) {         // wave-uniform branch
        float y = y_buf[n * 64 + c];           // 256B coalesced
        float v = fmaf(ab[c], y, ab[64 + c]);
        v = fmaxf(v, 0.f);
        out[c * HWC + py * WDIM + px] = v;
    }
}

// ---------------------------------------------------------------------------
extern "C" void kernel_launch(void* const* d_in, const int* in_sizes, int n_in,
                              void* d_out, int out_size, void* d_ws, size_t ws_size,
                              hipStream_t stream) {
    const float* feat   = (const float*)d_in[0];   // [1,64,256,1216]
    const float* diff   = (const float*)d_in[1];   // [1,40000,9,3]
    const int*   pix    = (const int*)  d_in[2];   // [1,40000,2]
    const int*   nnpix  = (const int*)  d_in[3];   // [1,40000,9,2]
    const float* W1     = (const float*)d_in[4];   // [3,32]
    const float* b1v    = (const float*)d_in[5];   // [32]
    const float* W2     = (const float*)d_in[6];   // [32,64]
    const float* b2v    = (const float*)d_in[7];   // [64]
    const float* conv_w = (const float*)d_in[8];   // [64,64]
    const float* conv_b = (const float*)d_in[9];   // [64]
    const float* gamma  = (const float*)d_in[10];  // [64]
    const float* beta   = (const float*)d_in[11];  // [64]
    float* out = (float*)d_out;

    // workspace layout (bytes):
    //   feat_t : 0          .. 16777216   (256*256*64 f32)
    //   y_buf  : 16777216   .. 27017216   (40000*64 f32)
    //   sums   : 27017216   .. 27017728   (128 f32)
    //   ab     : 27017728   .. 27018240   (128 f32)
    //   winner : 27018240   .. 27280384   (256*256 i32)
    char* ws = (char*)d_ws;
    float* feat_t = (float*)(ws);
    float* y_buf  = (float*)(ws + 16777216);
    float* sums   = (float*)(ws + 27017216);
    float* ab     = (float*)(ws + 27017728);
    int*   winner = (int*)  (ws + 27018240);

    hipMemsetAsync(d_out, 0, (size_t)out_size * sizeof(float), stream);
    hipMemsetAsync(sums, 0, 128 * sizeof(float), stream);
    hipMemsetAsync(winner, 0xFF, PIXR * PIXR * sizeof(int), stream);  // -1

    transpose_feat<<<1024, 256, 0, stream>>>(feat, feat_t);
    winner_k<<<(NPTS + 255) / 256, 256, 0, stream>>>(pix, winner);
    main_k<<<2500, 256, 0, stream>>>(feat_t, diff, nnpix, W1, b1v, W2, b2v,
                                     conv_w, conv_b, y_buf, sums);
    stats_k<<<1, 64, 0, stream>>>(sums, gamma, beta, ab);
    apply_k<<<NPTS / 4, 256, 0, stream>>>(y_buf, ab, pix, winner, out);
}

// Round 3
// 356.233 us; speedup vs baseline: 1.1309x; 1.1309x over previous
//
#include <hip/hip_runtime.h>

// Problem constants
#define HDIM 256
#define WDIM 1216
#define HWC  (HDIM*WDIM)     // 311296
#define NPTS 40000
#define KNN  9
#define CCH  64
#define PIXR 256             // index range of pixel coords (0..255)

typedef float v2f __attribute__((ext_vector_type(2)));

static __device__ __forceinline__ v2f mk2(float a, float b) { v2f r; r.x = a; r.y = b; return r; }

// ---------------------------------------------------------------------------
// Kernel 1: transpose accessed feature subregion CHW -> (iy,ix,c), ix<256.
// LDS-tiled: coalesced 256B reads AND writes; +1 pad kills bank conflicts.
// ---------------------------------------------------------------------------
__global__ __launch_bounds__(256) void transpose_feat(const float* __restrict__ feat,
                                                      float* __restrict__ feat_t) {
    __shared__ float tile[64][65];
    const int iy   = blockIdx.x >> 2;
    const int ixb  = (blockIdx.x & 3) * 64;
    const int lane = threadIdx.x & 63;
    const int w    = threadIdx.x >> 6;
#pragma unroll
    for (int r = 0; r < 16; ++r) {
        int cc = w * 16 + r;
        tile[cc][lane] = feat[cc * HWC + iy * WDIM + ixb + lane];   // 256B coalesced
    }
    __syncthreads();
#pragma unroll
    for (int r = 0; r < 16; ++r) {
        int ix = w * 16 + r;
        feat_t[(iy * PIXR + ixb + ix) * 64 + lane] = tile[lane][ix]; // 256B coalesced
    }
}

// ---------------------------------------------------------------------------
// Kernel 2: last-wins winner per output pixel (numpy fancy-assignment semantics)
// ---------------------------------------------------------------------------
__global__ void winner_k(const int* __restrict__ pix, int* __restrict__ winner) {
    int n = blockIdx.x * 256 + threadIdx.x;
    if (n < NPTS) {
        int px = pix[2 * n];
        int py = pix[2 * n + 1];
        atomicMax(&winner[py * PIXR + px], n);
    }
}

// ---------------------------------------------------------------------------
// Kernel 3: msg kernel. Wave per point, lane = channel c.
//  - MLP 3->32 (relu) ->64 (relu) per neighbor, per-lane (w2col in 32 VGPRs)
//  - weighted gather-sum over 9 neighbors -> msg[n,c]
// No LDS, no barriers, no conv_w registers -> ~90 VGPR, no spills at (256,4).
// Grid: 2500 blocks x 256 threads; each wave handles 4 points.
// ---------------------------------------------------------------------------
__global__ __launch_bounds__(256, 4) void msg_k(
    const float* __restrict__ feat_t,   // [256*256, 64]
    const float* __restrict__ diff,     // [N, 9, 3]
    const int*   __restrict__ nnpix,    // [N, 9, 2]
    const float* __restrict__ W1,       // [3, 32]
    const float* __restrict__ b1,       // [32]
    const float* __restrict__ W2,       // [32, 64]
    const float* __restrict__ b2,       // [64]
    float* __restrict__ msg_buf)        // [N, 64]
{
    const int c = threadIdx.x & 63;
    const int w = __builtin_amdgcn_readfirstlane(threadIdx.x >> 6);   // wave id, scalar

    float w2col[32];                       // W2[:, c] — the only persistent array
#pragma unroll
    for (int j = 0; j < 32; ++j) w2col[j] = W2[j * 64 + c];
    const float b2c = b2[c];

    for (int g = 0; g < 4; ++g) {
        const int n = blockIdx.x * 16 + g * 4 + w;   // scalar point index

        // --- issue gather loads early (latency hidden under MLP compute) ---
        const int* qi = nnpix + n * 18;              // wave-uniform -> s_load
        float fval[KNN];
#pragma unroll
        for (int k = 0; k < KNN; ++k) {
            int ix = qi[2 * k];
            int iy = qi[2 * k + 1];
            fval[k] = feat_t[(iy * PIXR + ix) * 64 + c];   // 256B coalesced
        }

        // --- load 9x3 offsets (wave-uniform -> s_load), pack k-pairs for pk_fma ---
        const float* pp = diff + n * 27;
        v2f P0[4], P1[4], P2[4];
#pragma unroll
        for (int kp = 0; kp < 4; ++kp) {
            P0[kp] = mk2(pp[6 * kp + 0], pp[6 * kp + 3]);
            P1[kp] = mk2(pp[6 * kp + 1], pp[6 * kp + 4]);
            P2[kp] = mk2(pp[6 * kp + 2], pp[6 * kp + 5]);
        }
        const float p0t = pp[24], p1t = pp[25], p2t = pp[26];

        v2f acc2[4];
#pragma unroll
        for (int kp = 0; kp < 4; ++kp) acc2[kp] = mk2(b2c, b2c);
        float acc8 = b2c;

        // --- MLP: j outer (W1/b1 wave-uniform -> s_loads), k inner ---
#pragma unroll
        for (int j = 0; j < 32; ++j) {
            const float w10 = W1[j], w11 = W1[32 + j], w12 = W1[64 + j], bj = b1[j];
            const float w2v = w2col[j];
            const v2f w10p = mk2(w10, w10), w11p = mk2(w11, w11), w12p = mk2(w12, w12);
            const v2f bjp = mk2(bj, bj), w2p = mk2(w2v, w2v);
#pragma unroll
            for (int kp = 0; kp < 4; ++kp) {
                v2f hm = P0[kp] * w10p + P1[kp] * w11p + P2[kp] * w12p + bjp;
                hm = __builtin_elementwise_max(hm, mk2(0.f, 0.f));
                acc2[kp] += hm * w2p;
            }
            float hm8 = fmaf(p0t, w10, fmaf(p1t, w11, fmaf(p2t, w12, bj)));
            hm8 = fmaxf(hm8, 0.f);
            acc8 = fmaf(hm8, w2v, acc8);
        }

        // --- weighted neighbor sum: msg[c] = sum_k relu(wts) * f ---
        float wk[KNN];
        wk[0] = acc2[0].x; wk[1] = acc2[0].y; wk[2] = acc2[1].x; wk[3] = acc2[1].y;
        wk[4] = acc2[2].x; wk[5] = acc2[2].y; wk[6] = acc2[3].x; wk[7] = acc2[3].y;
        wk[8] = acc8;
        float msg = 0.f;
#pragma unroll
        for (int k = 0; k < KNN; ++k) msg = fmaf(fmaxf(wk[k], 0.f), fval[k], msg);

        msg_buf[n * 64 + c] = msg;                    // 256B coalesced
    }
}

// ---------------------------------------------------------------------------
// Kernel 4: 1x1 conv + BN partial sums. Wave per point, lane = out-channel c.
// conv row in 64 VGPRs amortized over 32 points; msg broadcast via wave-private
// LDS (no barriers). Grid: 1250 blocks x 256 threads (32 points/block).
// ---------------------------------------------------------------------------
__global__ __launch_bounds__(256, 2) void conv_k(
    const float* __restrict__ msg_buf,  // [N, 64]
    const float* __restrict__ conv_w,   // [64, 64] (out, in)
    const float* __restrict__ conv_b,   // [64]
    float* __restrict__ y_buf,          // [N, 64]
    float* __restrict__ sums)           // [128]: sum(y), sum(y^2) per channel
{
    __shared__ float msg_lds[4][64];
    __shared__ float r1[4][64];
    __shared__ float r2[4][64];

    const int c = threadIdx.x & 63;
    const int w = __builtin_amdgcn_readfirstlane(threadIdx.x >> 6);

    float4 cw[16];                         // conv_w[c, :]
    const float4* cwrow = (const float4*)(conv_w + c * 64);
#pragma unroll
    for (int q = 0; q < 16; ++q) cw[q] = cwrow[q];
    const float cbc = conv_b[c];

    float s1 = 0.f, s2 = 0.f;

    for (int g = 0; g < 8; ++g) {
        const int n = blockIdx.x * 32 + g * 4 + w;   // scalar point index
        float m = msg_buf[n * 64 + c];               // 256B coalesced
        msg_lds[w][c] = m;                           // wave-private, no barrier
        float y = cbc;
        const float4* ml = (const float4*)msg_lds[w];
#pragma unroll
        for (int q = 0; q < 16; ++q) {
            float4 m4 = ml[q];                       // LDS broadcast reads
            float4 c4 = cw[q];
            y = fmaf(m4.x, c4.x, y);
            y = fmaf(m4.y, c4.y, y);
            y = fmaf(m4.z, c4.z, y);
            y = fmaf(m4.w, c4.w, y);
        }
        s1 += y;
        s2 = fmaf(y, y, s2);
        y_buf[n * 64 + c] = y;
    }

    // --- block reduction of BN partials, one atomicAdd pair per lane of wave 0 ---
    r1[w][c] = s1;
    r2[w][c] = s2;
    __syncthreads();
    if (w == 0) {
        float a  = r1[0][c] + r1[1][c] + r1[2][c] + r1[3][c];
        float bb = r2[0][c] + r2[1][c] + r2[2][c] + r2[3][c];
        atomicAdd(&sums[c], a);
        atomicAdd(&sums[64 + c], bb);
    }
}

// ---------------------------------------------------------------------------
// Kernel 5: fold BN stats into per-channel affine: A = gamma*rstd, B = beta - mean*A
// ---------------------------------------------------------------------------
__global__ void stats_k(const float* __restrict__ sums, const float* __restrict__ gamma,
                        const float* __restrict__ beta, float* __restrict__ ab) {
    int c = threadIdx.x;
    const float inv_n = 1.f / (float)NPTS;
    float mean = sums[c] * inv_n;
    float var  = sums[64 + c] * inv_n - mean * mean;
    float rstd = rsqrtf(var + 1e-5f);
    float A = gamma[c] * rstd;
    ab[c] = A;
    ab[64 + c] = beta[c] - mean * A;
}

// ---------------------------------------------------------------------------
// Kernel 6: BN apply + relu + last-wins scatter. Wave per point: pix/winner
// loads wave-uniform (scalar), y_buf read coalesced, skipped for losers.
// ---------------------------------------------------------------------------
__global__ __launch_bounds__(256) void apply_k(const float* __restrict__ y_buf,
                                               const float* __restrict__ ab,
                                               const int* __restrict__ pix,
                                               const int* __restrict__ winner,
                                               float* __restrict__ out) {
    const int c = threadIdx.x & 63;
    const int w = __builtin_amdgcn_readfirstlane(threadIdx.x >> 6);
    const int n = blockIdx.x * 4 + w;          // scalar point index
    const int px = pix[2 * n];                 // wave-uniform -> s_load
    const int py = pix[2 * n + 1];
    if (winner[py * PIXR + px] == n) {         // wave-uniform branch
        float y = y_buf[n * 64 + c];           // 256B coalesced
        float v = fmaf(ab[c], y, ab[64 + c]);
        v = fmaxf(v, 0.f);
        out[c * HWC + py * WDIM + px] = v;
    }
}

// ---------------------------------------------------------------------------
extern "C" void kernel_launch(void* const* d_in, const int* in_sizes, int n_in,
                              void* d_out, int out_size, void* d_ws, size_t ws_size,
                              hipStream_t stream) {
    const float* feat   = (const float*)d_in[0];   // [1,64,256,1216]
    const float* diff   = (const float*)d_in[1];   // [1,40000,9,3]
    const int*   pix    = (const int*)  d_in[2];   // [1,40000,2]
    const int*   nnpix  = (const int*)  d_in[3];   // [1,40000,9,2]
    const float* W1     = (const float*)d_in[4];   // [3,32]
    const float* b1v    = (const float*)d_in[5];   // [32]
    const float* W2     = (const float*)d_in[6];   // [32,64]
    const float* b2v    = (const float*)d_in[7];   // [64]
    const float* conv_w = (const float*)d_in[8];   // [64,64]
    const float* conv_b = (const float*)d_in[9];   // [64]
    const float* gamma  = (const float*)d_in[10];  // [64]
    const float* beta   = (const float*)d_in[11];  // [64]
    float* out = (float*)d_out;

    // workspace layout (bytes):
    //   feat_t : 0          .. 16777216   (256*256*64 f32)
    //   msg    : 16777216   .. 27017216   (40000*64 f32)
    //   y_buf  : 27017216   .. 37257216   (40000*64 f32)
    //   sums   : 37257216   .. 37257728   (128 f32)
    //   ab     : 37257728   .. 37258240   (128 f32)
    //   winner : 37258240   .. 37520384   (256*256 i32)
    char* ws = (char*)d_ws;
    float* feat_t  = (float*)(ws);
    float* msg_buf = (float*)(ws + 16777216);
    float* y_buf   = (float*)(ws + 27017216);
    float* sums    = (float*)(ws + 37257216);
    float* ab      = (float*)(ws + 37257728);
    int*   winner  = (int*)  (ws + 37258240);

    hipMemsetAsync(d_out, 0, (size_t)out_size * sizeof(float), stream);
    hipMemsetAsync(sums, 0, 128 * sizeof(float), stream);
    hipMemsetAsync(winner, 0xFF, PIXR * PIXR * sizeof(int), stream);  // -1

    transpose_feat<<<1024, 256, 0, stream>>>(feat, feat_t);
    winner_k<<<(NPTS + 255) / 256, 256, 0, stream>>>(pix, winner);
    msg_k<<<2500, 256, 0, stream>>>(feat_t, diff, nnpix, W1, b1v, W2, b2v, msg_buf);
    conv_k<<<1250, 256, 0, stream>>>(msg_buf, conv_w, conv_b, y_buf, sums);
    stats_k<<<1, 64, 0, stream>>>(sums, gamma, beta, ab);
    apply_k<<<NPTS / 4, 256, 0, stream>>>(y_buf, ab, pix, winner, out);
}

// Round 5
// 246.402 us; speedup vs baseline: 1.6350x; 1.4457x over previous
//
#include <hip/hip_runtime.h>

// Problem constants
#define HDIM 256
#define WDIM 1216
#define HWC  (HDIM*WDIM)     // 311296
#define NPTS 40000
#define KNN  9
#define CCH  64
#define PIXR 256             // index range of pixel coords (0..255)

// ---------------------------------------------------------------------------
// Kernel 1: transpose accessed feature subregion CHW -> (iy,ix,c), ix<256.
// LDS-tiled: coalesced 256B reads AND writes; +1 pad kills bank conflicts.
// ---------------------------------------------------------------------------
__global__ __launch_bounds__(256) void transpose_feat(const float* __restrict__ feat,
                                                      float* __restrict__ feat_t) {
    __shared__ float tile[64][65];
    const int iy   = blockIdx.x >> 2;
    const int ixb  = (blockIdx.x & 3) * 64;
    const int lane = threadIdx.x & 63;
    const int w    = threadIdx.x >> 6;
#pragma unroll
    for (int r = 0; r < 16; ++r) {
        int cc = w * 16 + r;
        tile[cc][lane] = feat[cc * HWC + iy * WDIM + ixb + lane];   // 256B coalesced
    }
    __syncthreads();
#pragma unroll
    for (int r = 0; r < 16; ++r) {
        int ix = w * 16 + r;
        feat_t[(iy * PIXR + ixb + ix) * 64 + lane] = tile[lane][ix]; // 256B coalesced
    }
}

// ---------------------------------------------------------------------------
// Kernel 2: last-wins winner per output pixel (numpy fancy-assignment semantics)
// ---------------------------------------------------------------------------
__global__ void winner_k(const int* __restrict__ pix, int* __restrict__ winner) {
    int n = blockIdx.x * 256 + threadIdx.x;
    if (n < NPTS) {
        int px = pix[2 * n];
        int py = pix[2 * n + 1];
        atomicMax(&winner[py * PIXR + px], n);
    }
}

// ---------------------------------------------------------------------------
// Kernel 3: fused msg kernel. Wave per point, 4 points/wave, 16/block.
// Phase A: hmid (288 vals/point) computed ONCE per wave into wave-private LDS
//          (lane covers idx = l, l+64, ... ; j = l&31 -> fixed W1 column).
// Phase B: lane = channel c; wts[k,c] = relu(b2 + sum_j hmid[k,j]*W2[j,c])
//          with hmid via ds_read_b128 broadcasts; msg = sum_k wts*gathered f.
// Wave-private LDS + in-order DS pipe -> NO barriers anywhere.
// Workspace: NO global hmid buffer (fits proven 37.5 MB footprint).
// ---------------------------------------------------------------------------
__global__ __launch_bounds__(256, 4) void msg_k(
    const float* __restrict__ feat_t,   // [256*256, 64]
    const float* __restrict__ diff,     // [N, 9, 3]
    const int*   __restrict__ nnpix,    // [N, 9, 2]
    const float* __restrict__ W1,       // [3, 32]
    const float* __restrict__ b1,       // [32]
    const float* __restrict__ W2,       // [32, 64]
    const float* __restrict__ b2,       // [64]
    float* __restrict__ msg_buf)        // [N, 64]
{
    __shared__ float dstage[4][32];     // diff staging (27 used), wave-private
    __shared__ float hl[4][288];        // hmid, wave-private

    const int l = threadIdx.x & 63;
    const int w = __builtin_amdgcn_readfirstlane(threadIdx.x >> 6);  // scalar
    const int c = l;

    // phase-A per-lane W1 column (j = l&31, loop-invariant)
    const int j = l & 31;
    const float w10 = W1[j], w11 = W1[32 + j], w12 = W1[64 + j], bj = b1[j];

    // phase-B per-lane W2 column
    float w2col[32];                       // W2[:, c]
#pragma unroll
    for (int jj = 0; jj < 32; ++jj) w2col[jj] = W2[jj * 64 + c];
    const float b2c = b2[c];

    for (int g = 0; g < 4; ++g) {
        const int n = blockIdx.x * 16 + g * 4 + w;   // scalar point index

        // --- gather neighbor features early (latency hidden under phase A/B) ---
        const int* qi = nnpix + n * 18;              // wave-uniform -> s_load
        float fval[KNN];
#pragma unroll
        for (int k = 0; k < KNN; ++k) {
            int ix = qi[2 * k];
            int iy = qi[2 * k + 1];
            fval[k] = feat_t[(iy * PIXR + ix) * 64 + c];   // 256B coalesced
        }

        // --- phase A: hmid[idx = k*32+j] = relu(diff[n][k].W1[:,j] + b1[j]) ---
        if (l < 27) dstage[w][l] = diff[n * 27 + l]; // wave-private stage
#pragma unroll
        for (int i = 0; i < 5; ++i) {
            int idx = l + 64 * i;
            if (idx < 288) {
                int k = idx >> 5;
                float d0 = dstage[w][k * 3 + 0];
                float d1 = dstage[w][k * 3 + 1];
                float d2 = dstage[w][k * 3 + 2];
                float h = fmaf(d0, w10, fmaf(d1, w11, fmaf(d2, w12, bj)));
                hl[w][idx] = fmaxf(h, 0.f);
            }
        }

        // --- phase B: wts + weighted neighbor sum (hmid via b128 broadcast) ---
        const float4* hp = (const float4*)hl[w];
        float msg = 0.f;
#pragma unroll
        for (int k = 0; k < KNN; ++k) {
            float a0 = b2c, a1 = 0.f, a2 = 0.f, a3 = 0.f;  // 4 chains
#pragma unroll
            for (int q = 0; q < 8; ++q) {
                float4 h = hp[k * 8 + q];                  // ds_read_b128 broadcast
                a0 = fmaf(h.x, w2col[4 * q + 0], a0);
                a1 = fmaf(h.y, w2col[4 * q + 1], a1);
                a2 = fmaf(h.z, w2col[4 * q + 2], a2);
                a3 = fmaf(h.w, w2col[4 * q + 3], a3);
            }
            float wt = fmaxf((a0 + a1) + (a2 + a3), 0.f);
            msg = fmaf(wt, fval[k], msg);
        }
        msg_buf[n * 64 + c] = msg;                    // 256B coalesced
    }
}

// ---------------------------------------------------------------------------
// Kernel 4: 1x1 conv + BN partial sums (exact R3 version — proven).
// Wave per point, lane = out-channel c; msg broadcast via wave-private LDS.
// ---------------------------------------------------------------------------
__global__ __launch_bounds__(256, 2) void conv_k(
    const float* __restrict__ msg_buf,  // [N, 64]
    const float* __restrict__ conv_w,   // [64, 64] (out, in)
    const float* __restrict__ conv_b,   // [64]
    float* __restrict__ y_buf,          // [N, 64]
    float* __restrict__ sums)           // [128]: sum(y), sum(y^2) per channel
{
    __shared__ float msg_lds[4][64];
    __shared__ float r1[4][64];
    __shared__ float r2[4][64];

    const int c = threadIdx.x & 63;
    const int w = __builtin_amdgcn_readfirstlane(threadIdx.x >> 6);

    float4 cw[16];                         // conv_w[c, :]
    const float4* cwrow = (const float4*)(conv_w + c * 64);
#pragma unroll
    for (int q = 0; q < 16; ++q) cw[q] = cwrow[q];
    const float cbc = conv_b[c];

    float s1 = 0.f, s2 = 0.f;

    for (int g = 0; g < 8; ++g) {
        const int n = blockIdx.x * 32 + g * 4 + w;   // scalar point index
        float m = msg_buf[n * 64 + c];               // 256B coalesced
        msg_lds[w][c] = m;                           // wave-private, no barrier
        float y = cbc;
        const float4* ml = (const float4*)msg_lds[w];
#pragma unroll
        for (int q = 0; q < 16; ++q) {
            float4 m4 = ml[q];                       // LDS broadcast reads
            float4 c4 = cw[q];
            y = fmaf(m4.x, c4.x, y);
            y = fmaf(m4.y, c4.y, y);
            y = fmaf(m4.z, c4.z, y);
            y = fmaf(m4.w, c4.w, y);
        }
        s1 += y;
        s2 = fmaf(y, y, s2);
        y_buf[n * 64 + c] = y;
    }

    r1[w][c] = s1;
    r2[w][c] = s2;
    __syncthreads();
    if (w == 0) {
        float a  = r1[0][c] + r1[1][c] + r1[2][c] + r1[3][c];
        float bb = r2[0][c] + r2[1][c] + r2[2][c] + r2[3][c];
        atomicAdd(&sums[c], a);
        atomicAdd(&sums[64 + c], bb);
    }
}

// ---------------------------------------------------------------------------
// Kernel 5: fold BN stats into per-channel affine: A = gamma*rstd, B = beta - mean*A
// ---------------------------------------------------------------------------
__global__ void stats_k(const float* __restrict__ sums, const float* __restrict__ gamma,
                        const float* __restrict__ beta, float* __restrict__ ab) {
    int c = threadIdx.x;
    const float inv_n = 1.f / (float)NPTS;
    float mean = sums[c] * inv_n;
    float var  = sums[64 + c] * inv_n - mean * mean;
    float rstd = rsqrtf(var + 1e-5f);
    float A = gamma[c] * rstd;
    ab[c] = A;
    ab[64 + c] = beta[c] - mean * A;
}

// ---------------------------------------------------------------------------
// Kernel 6: full-image writer. Block = (c,y) output row; lanes along x ->
// every store coalesced. Replaces memset(out) + scatter apply: x<256 takes
// BN(y_buf[winner]) or 0; x in [256,1216) zeroed with float4 stores.
// ---------------------------------------------------------------------------
__global__ __launch_bounds__(256) void write_k(
    const float* __restrict__ y_buf,   // [N, 64] pre-BN
    const float* __restrict__ ab,      // [128] affine
    const int*   __restrict__ winner,  // [256*256]
    float* __restrict__ out)           // [64, 256, 1216]
{
    const int c = blockIdx.x & 63;
    const int y = blockIdx.x >> 6;
    const int t = threadIdx.x;
    const float A = ab[c], B = ab[64 + c];     // wave-uniform -> s_load
    float* row = out + c * HWC + y * WDIM;

    int wn = winner[y * PIXR + t];             // coalesced 1KB
    float v = 0.f;
    if (wn >= 0) {
        float yv = y_buf[wn * 64 + c];         // scattered 4B (L2/L3)
        v = fmaxf(fmaf(A, yv, B), 0.f);
    }
    row[t] = v;                                // coalesced 1KB
    if (t < 240) {                             // zero x = 256..1215
        float4 z = {0.f, 0.f, 0.f, 0.f};
        ((float4*)(row + 256))[t] = z;         // coalesced 3840B
    }
}

// ---------------------------------------------------------------------------
extern "C" void kernel_launch(void* const* d_in, const int* in_sizes, int n_in,
                              void* d_out, int out_size, void* d_ws, size_t ws_size,
                              hipStream_t stream) {
    const float* feat   = (const float*)d_in[0];   // [1,64,256,1216]
    const float* diff   = (const float*)d_in[1];   // [1,40000,9,3]
    const int*   pix    = (const int*)  d_in[2];   // [1,40000,2]
    const int*   nnpix  = (const int*)  d_in[3];   // [1,40000,9,2]
    const float* W1     = (const float*)d_in[4];   // [3,32]
    const float* b1v    = (const float*)d_in[5];   // [32]
    const float* W2     = (const float*)d_in[6];   // [32,64]
    const float* b2v    = (const float*)d_in[7];   // [64]
    const float* conv_w = (const float*)d_in[8];   // [64,64]
    const float* conv_b = (const float*)d_in[9];   // [64]
    const float* gamma  = (const float*)d_in[10];  // [64]
    const float* beta   = (const float*)d_in[11];  // [64]
    float* out = (float*)d_out;

    // workspace layout (bytes) — EXACT R3 footprint (37,520,384 B, proven):
    //   feat_t : 0        .. 16777216    (256*256*64 f32)
    //   msg    : 16777216 .. 27017216    (40000*64 f32)
    //   y_buf  : 27017216 .. 37257216    (40000*64 f32)
    //   sums   : 37257216 .. 37257728
    //   ab     : 37257728 .. 37258240
    //   winner : 37258240 .. 37520384    (256*256 i32)
    char* ws = (char*)d_ws;
    float* feat_t  = (float*)(ws);
    float* msg_buf = (float*)(ws + 16777216);
    float* y_buf   = (float*)(ws + 27017216);
    float* sums    = (float*)(ws + 37257216);
    float* ab      = (float*)(ws + 37257728);
    int*   winner  = (int*)  (ws + 37258240);

    hipMemsetAsync(sums, 0, 128 * sizeof(float), stream);
    hipMemsetAsync(winner, 0xFF, PIXR * PIXR * sizeof(int), stream);  // -1

    transpose_feat<<<1024, 256, 0, stream>>>(feat, feat_t);
    winner_k<<<(NPTS + 255) / 256, 256, 0, stream>>>(pix, winner);
    msg_k<<<2500, 256, 0, stream>>>(feat_t, diff, nnpix, W1, b1v, W2, b2v, msg_buf);
    conv_k<<<1250, 256, 0, stream>>>(msg_buf, conv_w, conv_b, y_buf, sums);
    stats_k<<<1, 64, 0, stream>>>(sums, gamma, beta, ab);
    write_k<<<16384, 256, 0, stream>>>(y_buf, ab, winner, out);
}